// Round 1
// baseline (185.369 us; speedup 1.0000x reference)
//
#include <hip/hip_runtime.h>
#include <math.h>

// Shapes (fixed by the problem)
#define Hn 8
#define Sn 1024
#define Dn 64
#define KG 10

// Bias tables: dist in [0,10), energy in [0,5)
#define TN 2048
#define RD 10.25f
#define RE 5.125f

typedef __attribute__((ext_vector_type(8))) short bf16x8;
typedef __attribute__((ext_vector_type(4))) float f32x4;
typedef _Float16 f16;
typedef __attribute__((ext_vector_type(8))) _Float16 f16x8;
typedef unsigned short u16;
typedef unsigned int u32;

__device__ inline float bf2f(u16 u) {
    union { u32 i; float f; } v;
    v.i = ((u32)u) << 16;
    return v.f;
}

__device__ inline u16 f2bf(float f) {
    union { float f; u32 i; } v;
    v.f = f;
    u32 i = v.i;
    return (u16)((i + 0x7FFFu + ((i >> 16) & 1u)) >> 16);   // RNE
}

// ---------------------------------------------------------------------------
// RBF (10 gaussians) -> 10x10 MLP (exact gelu) -> scalar, all f32.
// ---------------------------------------------------------------------------
__device__ float bias_eval(float x,
                           const float* __restrict__ mu, const float* __restrict__ sg,
                           const float* __restrict__ bb,
                           const float* __restrict__ W1, const float* __restrict__ b1,
                           const float* __restrict__ W2, const float* __restrict__ b2) {
    const float inv_s2pi = 0.39894228040143267794f;
    float psi[KG];
#pragma unroll
    for (int k = 0; k < KG; k++) {
        float s = sg[k];
        float z = (x + bb[k] - mu[k]) / s;
        psi[k] = __expf(-0.5f * z * z) * (inv_s2pi / s);
    }
    float out = b2[0];
#pragma unroll
    for (int l = 0; l < KG; l++) {
        float a = b1[l];
#pragma unroll
        for (int k = 0; k < KG; k++) a += psi[k] * W1[l * KG + k];
        float g = 0.5f * a * (1.0f + erff(a * 0.70710678118654752440f));
        out += g * W2[l];
    }
    return out;
}

// ---------------------------------------------------------------------------
// Prepass 1:
//  ids [0, 2*TN)                 : bias interp tables (bf16 value | bf16 delta)
//  ids [2*TN, 2*TN+262144)       : Q,K f32 -> bf16 (float4 granularity)
//  ids [2*TN+262144, +524288)    : V -> bf16, transposed [h][d][s'] with the
//                                  k-permutation matching the P register order
// ---------------------------------------------------------------------------
#define QK4 262144              // (2*Hn*Sn*Dn)/4
#define VTN 524288              // Hn*Sn*Dn

__global__ __launch_bounds__(256) void prep_kernel(
    const float* __restrict__ Q, const float* __restrict__ K, const float* __restrict__ V,
    const float* __restrict__ muD, const float* __restrict__ sgD, const float* __restrict__ bD,
    const float* __restrict__ muE, const float* __restrict__ sgE, const float* __restrict__ bE,
    const float* __restrict__ W1, const float* __restrict__ b1,
    const float* __restrict__ W2, const float* __restrict__ b2,
    u32* __restrict__ tab, u16* __restrict__ Qb, u16* __restrict__ Kb, u16* __restrict__ VTi)
{
    int id = blockIdx.x * 256 + threadIdx.x;
    if (id < 2 * TN) {
        int which = (id >= TN);
        int idx = id & (TN - 1);
        float h = (which ? RE : RD) / (float)TN;
        float x0 = idx * h;
        float v0, v1;
        if (which) {
            v0 = bias_eval(x0,     muE, sgE, bE, W1, b1, W2, b2);
            v1 = bias_eval(x0 + h, muE, sgE, bE, W1, b1, W2, b2);
        } else {
            v0 = bias_eval(x0,     muD, sgD, bD, W1, b1, W2, b2);
            v1 = bias_eval(x0 + h, muD, sgD, bD, W1, b1, W2, b2);
        }
        tab[id] = (u32)f2bf(v0) | ((u32)f2bf(v1 - v0) << 16);
    } else if (id < 2 * TN + QK4) {
        int i = id - 2 * TN;
        int arr = i >> 17;          // 0 = Q, 1 = K
        i &= (1 << 17) - 1;
        float4 v = ((const float4*)(arr ? K : Q))[i];
        ushort4 o;
        o.x = f2bf(v.x); o.y = f2bf(v.y); o.z = f2bf(v.z); o.w = f2bf(v.w);
        ((ushort4*)(arr ? Kb : Qb))[i] = o;
    } else if (id < 2 * TN + QK4 + VTN) {
        int g = id - (2 * TN + QK4);
        int h = g >> 16;
        int d = (g >> 10) & 63;
        int s = g & 1023;
        int t = s >> 5, q = (s >> 3) & 3, j = s & 7;
        int src_s = (t << 5) + (q << 2) + (j & 3) + ((j >> 2) << 4);
        VTi[g] = f2bf(V[(((size_t)h << 10) + src_s) * Dn + d]);
    }
}

__device__ inline float lerp_tab(const u32* __restrict__ st, float x, float invh) {
    float tf = x * invh;
    int i = (int)tf;
    i = max(0, min(i, TN - 1));
    float fr = tf - (float)i;
    u32 p = st[i];
    return fmaf(bf2f((u16)(p >> 16)), fr, bf2f((u16)p));
}

// ---------------------------------------------------------------------------
// Prepass 2 (the heavy stream): fold Dm + Em + mask + both lerp tables into a
// single f16 combined-bias array Cb, stored in the exact (h,qb,wave,tile,lane)
// register order attn consumes, so attn does ONE coalesced 16 B load per tile.
//   group g -> lane=g&63, t=(g>>6)&7, w=(g>>9)&3, qb=(g>>11)&63, h=g>>17
//   element j of group: q = qb*16 + (lane&15),
//                       k = w*256 + t*32 + (lane>>4)*4 + (j<4 ? j : 16+j-4)
// Reads fully consume every 64B line; writes are perfectly contiguous.
// ---------------------------------------------------------------------------
#define CB_GROUPS (Hn * 64 * 4 * 8 * 64)    // H*S*S/8 = 1048576

__global__ __launch_bounds__(256) void bias_kernel(
    const float* __restrict__ Dm, const float* __restrict__ Em, const int* __restrict__ Mk,
    const u32* __restrict__ gtab, f16* __restrict__ Cb)
{
    __shared__ __align__(16) u32 sTab[2 * TN];      // 16 KB
    const int tid = threadIdx.x;
    {
        const uint4* g4 = (const uint4*)gtab;
        uint4* s4 = (uint4*)sTab;
#pragma unroll
        for (int i = 0; i < 4; i++) s4[tid + 256 * i] = g4[tid + 256 * i];
    }
    __syncthreads();
    const float invhD = (float)TN / RD;
    const float invhE = (float)TN / RE;

    for (int g = blockIdx.x * 256 + tid; g < CB_GROUPS; g += gridDim.x * 256) {
        const int lane = g & 63;
        const int t    = (g >> 6) & 7;
        const int w    = (g >> 9) & 3;
        const int qb   = (g >> 11) & 63;
        const int h    = g >> 17;
        const int q    = qb * 16 + (lane & 15);
        const int k    = w * 256 + t * 32 + (lane >> 4) * 4;
        const size_t base = ((((size_t)h << 10) + q) << 10) + k;

        const float4 d0 = *(const float4*)(Dm + base);
        const float4 d1 = *(const float4*)(Dm + base + 16);
        const float4 e0 = *(const float4*)(Em + base);
        const float4 e1 = *(const float4*)(Em + base + 16);
        const int4   m0 = *(const int4*)(Mk + base);
        const int4   m1 = *(const int4*)(Mk + base + 16);

        const float dv[8] = {d0.x, d0.y, d0.z, d0.w, d1.x, d1.y, d1.z, d1.w};
        const float ev[8] = {e0.x, e0.y, e0.z, e0.w, e1.x, e1.y, e1.z, e1.w};
        const int   mv[8] = {m0.x, m0.y, m0.z, m0.w, m1.x, m1.y, m1.z, m1.w};

        f16x8 o;
#pragma unroll
        for (int j = 0; j < 8; j++) {
            float b = lerp_tab(sTab, dv[j], invhD) + lerp_tab(sTab + TN, ev[j], invhE);
            // -60000 is exact in f16 and dominates qk*scale exactly like -1e9
            o[j] = (f16)((mv[j] == 0) ? -60000.0f : b);
        }
        ((f16x8*)Cb)[g] = o;
    }
}

// ---------------------------------------------------------------------------
// Fused flash attention, S^T formulation, now on a diet:
//  - all bias/mask work pre-folded into Cb (one 16 B f16x8 load per tile)
//  - explicit double-buffered register prefetch of K/V/bias for tile t+1,
//    so the ~9 loads/tile stay in flight instead of serializing at ~900 cy
// Grid (S/16, H), 256 threads = 4 waves; wave w covers k in [w*256,(w+1)*256).
// ---------------------------------------------------------------------------
__global__ __launch_bounds__(256) void attn_kernel(
    const u16* __restrict__ Qb, const u16* __restrict__ Kb, const u16* __restrict__ VTi,
    const f16* __restrict__ Cb, float* __restrict__ out)
{
    __shared__ float sO[4][16][68];                 // padded: conflict-free epilogue
    __shared__ float sM[4][16], sL[4][16];

    const int tid  = threadIdx.x;
    const int h    = blockIdx.y;
    const int qb   = blockIdx.x;
    const int q0   = qb * 16;
    const int wave = tid >> 6;
    const int lane = tid & 63;
    const int quad = lane >> 4;
    const int l16  = lane & 15;

    const u16* Qh = Qb  + (size_t)h * Sn * Dn;
    const u16* Kh = Kb  + (size_t)h * Sn * Dn;
    const u16* Vh = VTi + (size_t)h * Dn * Sn;
    const f16x8* Cw = (const f16x8*)Cb
                    + (size_t)(((h * 64 + qb) * 4 + wave) * 8) * 64 + lane;
    const float scale = 0.08838834764831845f;       // 1/sqrt(2*64)

    // Persistent Q B-fragments: B[n=l16][k=quad*8+j], k = d-dim
    const bf16x8 bQ0 = *(const bf16x8*)(Qh + (q0 + l16) * Dn + quad * 8);
    const bf16x8 bQ1 = *(const bf16x8*)(Qh + (q0 + l16) * Dn + 32 + quad * 8);

    f32x4 O0 = {0.f, 0.f, 0.f, 0.f}, O1 = O0, O2 = O0, O3 = O0;
    float m_run = -1e30f, l_run = 0.f;

    bf16x8 Ka[2][4];
    bf16x8 Va[2][4];
    f16x8  Ca[2];

#define LOADT(buf, tt) do {                                                   \
        const int k0_ = wave * 256 + (tt) * 32;                               \
        const u16* kr_ = Kh + (size_t)(k0_ + l16) * Dn + quad * 8;            \
        Ka[buf][0] = *(const bf16x8*)(kr_);                                   \
        Ka[buf][1] = *(const bf16x8*)(kr_ + 32);                              \
        Ka[buf][2] = *(const bf16x8*)(kr_ + 16 * Dn);                         \
        Ka[buf][3] = *(const bf16x8*)(kr_ + 16 * Dn + 32);                    \
        const u16* vr_ = Vh + k0_ + quad * 8 + (size_t)l16 * Sn;              \
        Va[buf][0] = *(const bf16x8*)(vr_);                                   \
        Va[buf][1] = *(const bf16x8*)(vr_ + 16 * Sn);                         \
        Va[buf][2] = *(const bf16x8*)(vr_ + 32 * Sn);                         \
        Va[buf][3] = *(const bf16x8*)(vr_ + 48 * Sn);                         \
        Ca[buf]    = Cw[(tt) * 64];                                           \
    } while (0)

    LOADT(0, 0);

#pragma unroll
    for (int t = 0; t < 8; t++) {
        const int cur = t & 1;
        if (t < 7) LOADT(cur ^ 1, t + 1);   // prefetch next tile: stays in flight

        f32x4 s0 = {0.f, 0.f, 0.f, 0.f}, s1 = s0;
        s0 = __builtin_amdgcn_mfma_f32_16x16x32_bf16(Ka[cur][0], bQ0, s0, 0, 0, 0);
        s0 = __builtin_amdgcn_mfma_f32_16x16x32_bf16(Ka[cur][1], bQ1, s0, 0, 0, 0);
        s1 = __builtin_amdgcn_mfma_f32_16x16x32_bf16(Ka[cur][2], bQ0, s1, 0, 0, 0);
        s1 = __builtin_amdgcn_mfma_f32_16x16x32_bf16(Ka[cur][3], bQ1, s1, 0, 0, 0);

        float sc0[4], sc1[4];
#pragma unroll
        for (int r = 0; r < 4; r++) {
            sc0[r] = fmaf(s0[r], scale, (float)Ca[cur][r]);
            sc1[r] = fmaf(s1[r], scale, (float)Ca[cur][4 + r]);
        }

        // row max: local over 8 values, then across quads (2 shuffles)
        float mloc = fmaxf(fmaxf(fmaxf(sc0[0], sc0[1]), fmaxf(sc0[2], sc0[3])),
                           fmaxf(fmaxf(sc1[0], sc1[1]), fmaxf(sc1[2], sc1[3])));
        mloc = fmaxf(mloc, __shfl_xor(mloc, 16, 64));
        mloc = fmaxf(mloc, __shfl_xor(mloc, 32, 64));

        const float mn = fmaxf(m_run, mloc);
        const float al = __expf(m_run - mn);
        m_run = mn;

        float p0[4], p1[4], ll = 0.f;
#pragma unroll
        for (int r = 0; r < 4; r++) {
            p0[r] = __expf(sc0[r] - mn);
            p1[r] = __expf(sc1[r] - mn);
            ll += p0[r] + p1[r];
        }
        ll += __shfl_xor(ll, 16, 64);
        ll += __shfl_xor(ll, 32, 64);
        l_run = l_run * al + ll;

        // P A-fragment straight from registers (k-order matches permuted V)
        bf16x8 aP;
#pragma unroll
        for (int r = 0; r < 4; r++) {
            aP[r]     = (short)f2bf(p0[r]);
            aP[4 + r] = (short)f2bf(p1[r]);
        }

        // O rescale: alpha for row quad*4+r lives in lane (quad*4+r)
        const float a0 = __shfl(al, quad * 4 + 0, 64);
        const float a1 = __shfl(al, quad * 4 + 1, 64);
        const float a2 = __shfl(al, quad * 4 + 2, 64);
        const float a3 = __shfl(al, quad * 4 + 3, 64);
        O0[0] *= a0; O0[1] *= a1; O0[2] *= a2; O0[3] *= a3;
        O1[0] *= a0; O1[1] *= a1; O1[2] *= a2; O1[3] *= a3;
        O2[0] *= a0; O2[1] *= a1; O2[2] *= a2; O2[3] *= a3;
        O3[0] *= a0; O3[1] *= a1; O3[2] *= a2; O3[3] *= a3;

        O0 = __builtin_amdgcn_mfma_f32_16x16x32_bf16(aP, Va[cur][0], O0, 0, 0, 0);
        O1 = __builtin_amdgcn_mfma_f32_16x16x32_bf16(aP, Va[cur][1], O1, 0, 0, 0);
        O2 = __builtin_amdgcn_mfma_f32_16x16x32_bf16(aP, Va[cur][2], O2, 0, 0, 0);
        O3 = __builtin_amdgcn_mfma_f32_16x16x32_bf16(aP, Va[cur][3], O3, 0, 0, 0);
    }
#undef LOADT

    // cross-wave combine (flash-2): O regs are [row=quad*4+r][d=vt*16+l16]
    if (lane < 16) {
        sM[wave][lane] = m_run;
        sL[wave][lane] = l_run;
    }
#pragma unroll
    for (int r = 0; r < 4; r++) {
        sO[wave][quad * 4 + r][ 0 + l16] = O0[r];
        sO[wave][quad * 4 + r][16 + l16] = O1[r];
        sO[wave][quad * 4 + r][32 + l16] = O2[r];
        sO[wave][quad * 4 + r][48 + l16] = O3[r];
    }
    __syncthreads();

    const int row = tid >> 4;
    const int c4  = (tid & 15) * 4;
    float mg = sM[0][row];
#pragma unroll
    for (int w = 1; w < 4; w++) mg = fmaxf(mg, sM[w][row]);
    float fac[4], lg = 0.f;
#pragma unroll
    for (int w = 0; w < 4; w++) {
        fac[w] = __expf(sM[w][row] - mg);
        lg += sL[w][row] * fac[w];
    }
    const float inv = 1.0f / lg;

    float acc[4];
#pragma unroll
    for (int c = 0; c < 4; c++) {
        acc[c] = 0.f;
#pragma unroll
        for (int w = 0; w < 4; w++) acc[c] += sO[w][row][c4 + c] * fac[w];
        acc[c] *= inv;
    }
    float4 ov = {acc[0], acc[1], acc[2], acc[3]};
    *(float4*)(out + ((size_t)(h * Sn + q0 + row)) * Dn + c4) = ov;
}

// ---------------------------------------------------------------------------
extern "C" void kernel_launch(void* const* d_in, const int* in_sizes, int n_in,
                              void* d_out, int out_size, void* d_ws, size_t ws_size,
                              hipStream_t stream) {
    const float* Q    = (const float*)d_in[0];
    const float* K    = (const float*)d_in[1];
    const float* V    = (const float*)d_in[2];
    const float* Dm   = (const float*)d_in[3];
    const float* Em   = (const float*)d_in[4];
    const int*   Mask = (const int*)d_in[5];
    const float* muD  = (const float*)d_in[6];
    const float* sgD  = (const float*)d_in[7];
    const float* bD   = (const float*)d_in[8];
    const float* muE  = (const float*)d_in[9];
    const float* sgE  = (const float*)d_in[10];
    const float* bE   = (const float*)d_in[11];
    const float* W1   = (const float*)d_in[12];
    const float* b1   = (const float*)d_in[13];
    const float* W2   = (const float*)d_in[14];
    const float* b2   = (const float*)d_in[15];

    // ws layout: tab 16 KB | Qb 1 MB | Kb 1 MB | VTi 1 MB | Cb 16 MB (~19.1 MB)
    u32* tab = (u32*)d_ws;
    u16* Qb  = (u16*)((char*)d_ws + 2 * TN * 4);
    u16* Kb  = Qb + (size_t)Hn * Sn * Dn;
    u16* VTi = Kb + (size_t)Hn * Sn * Dn;
    f16* Cb  = (f16*)(VTi + (size_t)Hn * Sn * Dn);

    const int prep_threads = 2 * TN + QK4 + VTN;           // 790528
    prep_kernel<<<prep_threads / 256, 256, 0, stream>>>(
        Q, K, V, muD, sgD, bD, muE, sgE, bE, W1, b1, W2, b2,
        tab, Qb, Kb, VTi);

    bias_kernel<<<2048, 256, 0, stream>>>(Dm, Em, Mask, tab, Cb);

    dim3 grid(Sn / 16, Hn);
    attn_kernel<<<grid, 256, 0, stream>>>(Qb, Kb, VTi, Cb, (float*)d_out);
}

// Round 2
// 175.840 us; speedup vs baseline: 1.0542x; 1.0542x over previous
//
#include <hip/hip_runtime.h>
#include <math.h>

// Shapes (fixed by the problem)
#define Hn 8
#define Sn 1024
#define Dn 64
#define KG 10

// Bias tables: dist in [0,10), energy in [0,5)
#define TN 2048
#define RD 10.25f
#define RE 5.125f

typedef __attribute__((ext_vector_type(8))) short bf16x8;
typedef __attribute__((ext_vector_type(4))) float f32x4;
typedef unsigned short u16;
typedef unsigned int u32;

__device__ inline float bf2f(u16 u) {
    union { u32 i; float f; } v;
    v.i = ((u32)u) << 16;
    return v.f;
}

__device__ inline u16 f2bf(float f) {
    union { float f; u32 i; } v;
    v.f = f;
    u32 i = v.i;
    return (u16)((i + 0x7FFFu + ((i >> 16) & 1u)) >> 16);   // RNE
}

// ---------------------------------------------------------------------------
// RBF (10 gaussians) -> 10x10 MLP (exact gelu) -> scalar, all f32.
// ---------------------------------------------------------------------------
__device__ float bias_eval(float x,
                           const float* __restrict__ mu, const float* __restrict__ sg,
                           const float* __restrict__ bb,
                           const float* __restrict__ W1, const float* __restrict__ b1,
                           const float* __restrict__ W2, const float* __restrict__ b2) {
    const float inv_s2pi = 0.39894228040143267794f;
    float psi[KG];
#pragma unroll
    for (int k = 0; k < KG; k++) {
        float s = sg[k];
        float z = (x + bb[k] - mu[k]) / s;
        psi[k] = __expf(-0.5f * z * z) * (inv_s2pi / s);
    }
    float out = b2[0];
#pragma unroll
    for (int l = 0; l < KG; l++) {
        float a = b1[l];
#pragma unroll
        for (int k = 0; k < KG; k++) a += psi[k] * W1[l * KG + k];
        float g = 0.5f * a * (1.0f + erff(a * 0.70710678118654752440f));
        out += g * W2[l];
    }
    return out;
}

// ---------------------------------------------------------------------------
// Fused prepass:
//  ids [0, 2*TN)                 : bias interp tables (bf16 value | bf16 delta)
//  ids [2*TN, 2*TN+262144)       : Q,K f32 -> bf16 (float4 granularity)
//  ids [2*TN+262144, +524288)    : V -> bf16, transposed [h][d][s'] with the
//                                  k-permutation matching the P register order
// ---------------------------------------------------------------------------
#define QK4 262144              // (2*Hn*Sn*Dn)/4
#define VTN 524288              // Hn*Sn*Dn

__global__ __launch_bounds__(256) void prep_kernel(
    const float* __restrict__ Q, const float* __restrict__ K, const float* __restrict__ V,
    const float* __restrict__ muD, const float* __restrict__ sgD, const float* __restrict__ bD,
    const float* __restrict__ muE, const float* __restrict__ sgE, const float* __restrict__ bE,
    const float* __restrict__ W1, const float* __restrict__ b1,
    const float* __restrict__ W2, const float* __restrict__ b2,
    u32* __restrict__ tab, u16* __restrict__ Qb, u16* __restrict__ Kb, u16* __restrict__ VTi)
{
    int id = blockIdx.x * 256 + threadIdx.x;
    if (id < 2 * TN) {
        int which = (id >= TN);
        int idx = id & (TN - 1);
        float h = (which ? RE : RD) / (float)TN;
        float x0 = idx * h;
        float v0, v1;
        if (which) {
            v0 = bias_eval(x0,     muE, sgE, bE, W1, b1, W2, b2);
            v1 = bias_eval(x0 + h, muE, sgE, bE, W1, b1, W2, b2);
        } else {
            v0 = bias_eval(x0,     muD, sgD, bD, W1, b1, W2, b2);
            v1 = bias_eval(x0 + h, muD, sgD, bD, W1, b1, W2, b2);
        }
        tab[id] = (u32)f2bf(v0) | ((u32)f2bf(v1 - v0) << 16);
    } else if (id < 2 * TN + QK4) {
        int i = id - 2 * TN;
        int arr = i >> 17;          // 0 = Q, 1 = K
        i &= (1 << 17) - 1;
        float4 v = ((const float4*)(arr ? K : Q))[i];
        ushort4 o;
        o.x = f2bf(v.x); o.y = f2bf(v.y); o.z = f2bf(v.z); o.w = f2bf(v.w);
        ((ushort4*)(arr ? Kb : Qb))[i] = o;
    } else if (id < 2 * TN + QK4 + VTN) {
        int g = id - (2 * TN + QK4);
        int h = g >> 16;
        int d = (g >> 10) & 63;
        int s = g & 1023;
        int t = s >> 5, q = (s >> 3) & 3, j = s & 7;
        int src_s = (t << 5) + (q << 2) + (j & 3) + ((j >> 2) << 4);
        VTi[g] = f2bf(V[(((size_t)h << 10) + src_s) * Dn + d]);
    }
}

__device__ inline float lerp_tab(const u32* __restrict__ st, float x, float invh) {
    float tf = x * invh;
    int i = (int)tf;
    i = max(0, min(i, TN - 1));
    float fr = tf - (float)i;
    u32 p = st[i];
    return fmaf(bf2f((u16)(p >> 16)), fr, bf2f((u16)p));
}

// ---------------------------------------------------------------------------
// Fused flash attention, S^T formulation, with explicit 2-deep register
// prefetch of ALL per-tile streams (K frags, V frags, D/E bias, mask).
// Grid (S/16, H) = 512 blocks -> grid-limited to 2 waves/SIMD, so VGPRs are
// free: the named double buffers (~112 VGPR) keep all 14 loads/tile in
// flight under the previous tile's MFMA+softmax instead of serializing at
// ~900 cy each (round-0 failure mode: 12.7K cy/tile).
// ---------------------------------------------------------------------------
__global__ __launch_bounds__(256) void attn_kernel(
    const u16* __restrict__ Qb, const u16* __restrict__ Kb, const u16* __restrict__ VTi,
    const float* __restrict__ Dm, const float* __restrict__ Em, const int* __restrict__ Mk,
    const u32* __restrict__ gtab, float* __restrict__ out)
{
    __shared__ __align__(16) u32 sTab[2 * TN];      // 16 KB
    __shared__ float sO[4][16][68];                 // padded: conflict-free epilogue
    __shared__ float sM[4][16], sL[4][16];

    const int tid = threadIdx.x;
    {   // stage tables: 1024 uint4 over 256 threads
        const uint4* g4 = (const uint4*)gtab;
        uint4* s4 = (uint4*)sTab;
#pragma unroll
        for (int i = 0; i < 4; i++) s4[tid + 256 * i] = g4[tid + 256 * i];
    }
    __syncthreads();

    const int h    = blockIdx.y;
    const int q0   = blockIdx.x * 16;
    const int wave = tid >> 6;
    const int lane = tid & 63;
    const int quad = lane >> 4;
    const int l16  = lane & 15;

    const u16* Qh = Qb  + (size_t)h * Sn * Dn;
    const u16* Kh = Kb  + (size_t)h * Sn * Dn;
    const u16* Vh = VTi + (size_t)h * Dn * Sn;
    const float* Dh = Dm + (size_t)h * Sn * Sn + (size_t)(q0 + l16) * Sn;
    const float* Eh = Em + (size_t)h * Sn * Sn + (size_t)(q0 + l16) * Sn;
    const int*   Mh = Mk + (size_t)h * Sn * Sn + (size_t)(q0 + l16) * Sn;
    const float invhD = (float)TN / RD;
    const float invhE = (float)TN / RE;
    const float scale = 0.08838834764831845f;       // 1/sqrt(2*64)

    // Persistent Q B-fragments: B[n=l16][k=quad*8+j], k = d-dim
    const bf16x8 bQ0 = *(const bf16x8*)(Qh + (q0 + l16) * Dn + quad * 8);
    const bf16x8 bQ1 = *(const bf16x8*)(Qh + (q0 + l16) * Dn + 32 + quad * 8);

    f32x4 O0 = {0.f, 0.f, 0.f, 0.f}, O1 = O0, O2 = O0, O3 = O0;
    float m_run = -1e30f, l_run = 0.f;

    bf16x8 Ka[2][4];
    bf16x8 Va[2][4];
    float4 Dv[2][2];
    float4 Ev[2][2];
    int4   Mv[2][2];

#define LOADT(buf, tt) do {                                                   \
        const int k0_ = wave * 256 + (tt) * 32;                               \
        const u16* kr_ = Kh + (size_t)(k0_ + l16) * Dn + quad * 8;            \
        Ka[buf][0] = *(const bf16x8*)(kr_);                                   \
        Ka[buf][1] = *(const bf16x8*)(kr_ + 32);                              \
        Ka[buf][2] = *(const bf16x8*)(kr_ + 16 * Dn);                         \
        Ka[buf][3] = *(const bf16x8*)(kr_ + 16 * Dn + 32);                    \
        const u16* vr_ = Vh + k0_ + quad * 8 + (size_t)l16 * Sn;              \
        Va[buf][0] = *(const bf16x8*)(vr_);                                   \
        Va[buf][1] = *(const bf16x8*)(vr_ + 16 * Sn);                         \
        Va[buf][2] = *(const bf16x8*)(vr_ + 32 * Sn);                         \
        Va[buf][3] = *(const bf16x8*)(vr_ + 48 * Sn);                         \
        Dv[buf][0] = *(const float4*)(Dh + k0_ + quad * 4);                   \
        Dv[buf][1] = *(const float4*)(Dh + k0_ + 16 + quad * 4);              \
        Ev[buf][0] = *(const float4*)(Eh + k0_ + quad * 4);                   \
        Ev[buf][1] = *(const float4*)(Eh + k0_ + 16 + quad * 4);              \
        Mv[buf][0] = *(const int4*)(Mh + k0_ + quad * 4);                     \
        Mv[buf][1] = *(const int4*)(Mh + k0_ + 16 + quad * 4);                \
    } while (0)

    LOADT(0, 0);

#pragma unroll
    for (int t = 0; t < 8; t++) {
        const int cur = t & 1;
        if (t < 7) LOADT(cur ^ 1, t + 1);   // prefetch next tile: stays in flight

        f32x4 s0 = {0.f, 0.f, 0.f, 0.f}, s1 = s0;
        s0 = __builtin_amdgcn_mfma_f32_16x16x32_bf16(Ka[cur][0], bQ0, s0, 0, 0, 0);
        s0 = __builtin_amdgcn_mfma_f32_16x16x32_bf16(Ka[cur][1], bQ1, s0, 0, 0, 0);
        s1 = __builtin_amdgcn_mfma_f32_16x16x32_bf16(Ka[cur][2], bQ0, s1, 0, 0, 0);
        s1 = __builtin_amdgcn_mfma_f32_16x16x32_bf16(Ka[cur][3], bQ1, s1, 0, 0, 0);

        const float dv0[4] = {Dv[cur][0].x, Dv[cur][0].y, Dv[cur][0].z, Dv[cur][0].w};
        const float dv1[4] = {Dv[cur][1].x, Dv[cur][1].y, Dv[cur][1].z, Dv[cur][1].w};
        const float ev0[4] = {Ev[cur][0].x, Ev[cur][0].y, Ev[cur][0].z, Ev[cur][0].w};
        const float ev1[4] = {Ev[cur][1].x, Ev[cur][1].y, Ev[cur][1].z, Ev[cur][1].w};
        const int   mv0[4] = {Mv[cur][0].x, Mv[cur][0].y, Mv[cur][0].z, Mv[cur][0].w};
        const int   mv1[4] = {Mv[cur][1].x, Mv[cur][1].y, Mv[cur][1].z, Mv[cur][1].w};

        float sc0[4], sc1[4];
#pragma unroll
        for (int r = 0; r < 4; r++) {
            float v0 = s0[r] * scale + lerp_tab(sTab, dv0[r], invhD)
                                     + lerp_tab(sTab + TN, ev0[r], invhE);
            v0 = fminf(fmaxf(v0, -80.f), 80.f);
            sc0[r] = (mv0[r] == 0) ? -1e9f : v0;
            float v1 = s1[r] * scale + lerp_tab(sTab, dv1[r], invhD)
                                     + lerp_tab(sTab + TN, ev1[r], invhE);
            v1 = fminf(fmaxf(v1, -80.f), 80.f);
            sc1[r] = (mv1[r] == 0) ? -1e9f : v1;
        }

        // row max: local over 8 values, then across quads (2 shuffles)
        float mloc = fmaxf(fmaxf(fmaxf(sc0[0], sc0[1]), fmaxf(sc0[2], sc0[3])),
                           fmaxf(fmaxf(sc1[0], sc1[1]), fmaxf(sc1[2], sc1[3])));
        mloc = fmaxf(mloc, __shfl_xor(mloc, 16, 64));
        mloc = fmaxf(mloc, __shfl_xor(mloc, 32, 64));

        const float mn = fmaxf(m_run, mloc);
        const float al = __expf(m_run - mn);
        m_run = mn;

        float p0[4], p1[4], ll = 0.f;
#pragma unroll
        for (int r = 0; r < 4; r++) {
            p0[r] = __expf(sc0[r] - mn);
            p1[r] = __expf(sc1[r] - mn);
            ll += p0[r] + p1[r];
        }
        ll += __shfl_xor(ll, 16, 64);
        ll += __shfl_xor(ll, 32, 64);
        l_run = l_run * al + ll;

        // P A-fragment straight from registers (k-order matches permuted V)
        bf16x8 aP;
#pragma unroll
        for (int r = 0; r < 4; r++) {
            aP[r]     = (short)f2bf(p0[r]);
            aP[4 + r] = (short)f2bf(p1[r]);
        }

        // O rescale: alpha for row quad*4+r lives in lane (quad*4+r)
        const float a0 = __shfl(al, quad * 4 + 0, 64);
        const float a1 = __shfl(al, quad * 4 + 1, 64);
        const float a2 = __shfl(al, quad * 4 + 2, 64);
        const float a3 = __shfl(al, quad * 4 + 3, 64);
        O0[0] *= a0; O0[1] *= a1; O0[2] *= a2; O0[3] *= a3;
        O1[0] *= a0; O1[1] *= a1; O1[2] *= a2; O1[3] *= a3;
        O2[0] *= a0; O2[1] *= a1; O2[2] *= a2; O2[3] *= a3;
        O3[0] *= a0; O3[1] *= a1; O3[2] *= a2; O3[3] *= a3;

        O0 = __builtin_amdgcn_mfma_f32_16x16x32_bf16(aP, Va[cur][0], O0, 0, 0, 0);
        O1 = __builtin_amdgcn_mfma_f32_16x16x32_bf16(aP, Va[cur][1], O1, 0, 0, 0);
        O2 = __builtin_amdgcn_mfma_f32_16x16x32_bf16(aP, Va[cur][2], O2, 0, 0, 0);
        O3 = __builtin_amdgcn_mfma_f32_16x16x32_bf16(aP, Va[cur][3], O3, 0, 0, 0);
    }
#undef LOADT

    // cross-wave combine (flash-2): O regs are [row=quad*4+r][d=vt*16+l16]
    if (lane < 16) {
        sM[wave][lane] = m_run;
        sL[wave][lane] = l_run;
    }
#pragma unroll
    for (int r = 0; r < 4; r++) {
        sO[wave][quad * 4 + r][ 0 + l16] = O0[r];
        sO[wave][quad * 4 + r][16 + l16] = O1[r];
        sO[wave][quad * 4 + r][32 + l16] = O2[r];
        sO[wave][quad * 4 + r][48 + l16] = O3[r];
    }
    __syncthreads();

    const int row = tid >> 4;
    const int c4  = (tid & 15) * 4;
    float mg = sM[0][row];
#pragma unroll
    for (int w = 1; w < 4; w++) mg = fmaxf(mg, sM[w][row]);
    float fac[4], lg = 0.f;
#pragma unroll
    for (int w = 0; w < 4; w++) {
        fac[w] = __expf(sM[w][row] - mg);
        lg += sL[w][row] * fac[w];
    }
    const float inv = 1.0f / lg;

    float acc[4];
#pragma unroll
    for (int c = 0; c < 4; c++) {
        acc[c] = 0.f;
#pragma unroll
        for (int w = 0; w < 4; w++) acc[c] += sO[w][row][c4 + c] * fac[w];
        acc[c] *= inv;
    }
    float4 ov = {acc[0], acc[1], acc[2], acc[3]};
    *(float4*)(out + ((size_t)(h * Sn + q0 + row)) * Dn + c4) = ov;
}

// ---------------------------------------------------------------------------
extern "C" void kernel_launch(void* const* d_in, const int* in_sizes, int n_in,
                              void* d_out, int out_size, void* d_ws, size_t ws_size,
                              hipStream_t stream) {
    const float* Q    = (const float*)d_in[0];
    const float* K    = (const float*)d_in[1];
    const float* V    = (const float*)d_in[2];
    const float* Dm   = (const float*)d_in[3];
    const float* Em   = (const float*)d_in[4];
    const int*   Mask = (const int*)d_in[5];
    const float* muD  = (const float*)d_in[6];
    const float* sgD  = (const float*)d_in[7];
    const float* bD   = (const float*)d_in[8];
    const float* muE  = (const float*)d_in[9];
    const float* sgE  = (const float*)d_in[10];
    const float* bE   = (const float*)d_in[11];
    const float* W1   = (const float*)d_in[12];
    const float* b1   = (const float*)d_in[13];
    const float* W2   = (const float*)d_in[14];
    const float* b2   = (const float*)d_in[15];

    // ws layout: tab 16 KB | Qb 1 MB | Kb 1 MB | VTi 1 MB  (~3.1 MB total)
    u32* tab = (u32*)d_ws;
    u16* Qb  = (u16*)((char*)d_ws + 2 * TN * 4);
    u16* Kb  = Qb + (size_t)Hn * Sn * Dn;
    u16* VTi = Kb + (size_t)Hn * Sn * Dn;

    const int prep_threads = 2 * TN + QK4 + VTN;           // 790528
    prep_kernel<<<prep_threads / 256, 256, 0, stream>>>(
        Q, K, V, muD, sgD, bD, muE, sgE, bE, W1, b1, W2, b2,
        tab, Qb, Kb, VTi);

    dim3 grid(Sn / 16, Hn);
    attn_kernel<<<grid, 256, 0, stream>>>(Qb, Kb, VTi, Dm, Em, Mask, tab,
                                          (float*)d_out);
}